// Round 1
// baseline (719.528 us; speedup 1.0000x reference)
//
#include <hip/hip_runtime.h>
#include <hip/hip_bf16.h>

#define N_FEAT 64

// ---------------- CSR build ----------------

__global__ __launch_bounds__(256) void init_nodes(float* deg, int* cnt, int* fill, int* cursor, int N) {
    int i = blockIdx.x * blockDim.x + threadIdx.x;
    if (i < N) { deg[i] = 1.0f; cnt[i] = 0; fill[i] = 0; }
    if (i == 0) cursor[0] = 0;
}

__global__ __launch_bounds__(256) void edge_deg(const int* __restrict__ ei, const float* __restrict__ ew,
                                                float* deg, int* cnt, int E) {
    int e = blockIdx.x * blockDim.x + threadIdx.x;
    if (e >= E) return;
    int dst = ei[E + e];
    atomicAdd(&deg[dst], ew[e]);
    atomicAdd(&cnt[dst], 1);
}

// per-wave scan of counts + atomic cursor to get row_ptr; also dis = rsqrt(deg)
__global__ __launch_bounds__(256) void node_scan(float* __restrict__ deg_dis, const int* __restrict__ cnt,
                                                 int* __restrict__ rowp, int* cursor, int N) {
    int i = blockIdx.x * blockDim.x + threadIdx.x;
    int lane = threadIdx.x & 63;
    int c = (i < N) ? cnt[i] : 0;
    int incl = c;
    #pragma unroll
    for (int o = 1; o < 64; o <<= 1) {
        int t = __shfl_up(incl, o);
        if (lane >= o) incl += t;
    }
    int total = __shfl(incl, 63);
    int base = 0;
    if (lane == 0) base = atomicAdd(cursor, total);
    base = __shfl(base, 0);
    if (i < N) {
        rowp[i] = base + incl - c;
        deg_dis[i] = rsqrtf(deg_dis[i]);   // deg >= 1 always (self loop)
    }
}

__global__ __launch_bounds__(256) void fill_csr(const int* __restrict__ ei, const float* __restrict__ ew,
                                                const float* __restrict__ dis, const int* __restrict__ rowp,
                                                int* fill, int* __restrict__ csr_s, float* __restrict__ csr_w,
                                                int E) {
    int e = blockIdx.x * blockDim.x + threadIdx.x;
    if (e >= E) return;
    int s = ei[e];
    int d = ei[E + e];
    int pos = rowp[d] + atomicAdd(&fill[d], 1);
    csr_s[pos] = s;
    csr_w[pos] = dis[s] * ew[e] * dis[d];
}

__global__ __launch_bounds__(256) void pad_w3(const float* __restrict__ W3, float* __restrict__ W3p) {
    int i = blockIdx.x * blockDim.x + threadIdx.x;   // 4096 threads
    if (i >= 64 * 64) return;
    int k = i >> 6, c = i & 63;
    W3p[i] = (c < 16) ? W3[k * 16 + c] : 0.0f;
}

// ---------------- GEMM: C[N x 64] = A[N x 64] @ W[64 x 64] ----------------

__global__ __launch_bounds__(256) void gemm64(const float* __restrict__ A, const float* __restrict__ W,
                                              float* __restrict__ C, int N) {
    __shared__ float At[64 * 68];   // transposed A tile, stride 68 (bank-conflict pad, 16B aligned)
    __shared__ float Wl[64 * 64];
    int tid = threadIdx.x;
    int r0 = blockIdx.x * 64;

    // stage W (4096 floats)
    for (int i = tid * 4; i < 4096; i += 1024) {
        *(float4*)&Wl[i] = *(const float4*)&W[i];
    }
    // stage A tile transposed: At[c][r]
    #pragma unroll
    for (int jj = 0; jj < 4; ++jj) {
        int r = (tid >> 4) + jj * 16;        // 0..63
        int c0 = (tid & 15) * 4;
        float4 v = make_float4(0.f, 0.f, 0.f, 0.f);
        if (r0 + r < N) v = *(const float4*)&A[(size_t)(r0 + r) * 64 + c0];
        At[(c0 + 0) * 68 + r] = v.x;
        At[(c0 + 1) * 68 + r] = v.y;
        At[(c0 + 2) * 68 + r] = v.z;
        At[(c0 + 3) * 68 + r] = v.w;
    }
    __syncthreads();

    int tr = tid >> 4, tc = tid & 15;        // 16x16 threads, 4x4 tile each
    float acc[4][4] = {};
    #pragma unroll
    for (int k = 0; k < 64; ++k) {
        float4 a = *(const float4*)&At[k * 68 + 4 * tr];
        float4 w = *(const float4*)&Wl[k * 64 + 4 * tc];
        float av[4] = {a.x, a.y, a.z, a.w};
        float wv[4] = {w.x, w.y, w.z, w.w};
        #pragma unroll
        for (int i = 0; i < 4; ++i)
            #pragma unroll
            for (int j = 0; j < 4; ++j)
                acc[i][j] = fmaf(av[i], wv[j], acc[i][j]);
    }

    #pragma unroll
    for (int i = 0; i < 4; ++i) {
        int r = r0 + 4 * tr + i;
        if (r < N) {
            float4 v = make_float4(acc[i][0], acc[i][1], acc[i][2], acc[i][3]);
            *(float4*)&C[(size_t)r * 64 + 4 * tc] = v;
        }
    }
}

// ---------------- Aggregation: out[n] = sum_{e->n} w_e * hw[src_e] + dis[n]^2*hw[n] + b ----------------

template<int F, bool RELU, bool DUP>
__global__ __launch_bounds__(256) void aggregate(const float* __restrict__ hw, const int* __restrict__ rowp,
                                                 const int* __restrict__ cnt, const int* __restrict__ csr_s,
                                                 const float* __restrict__ csr_w, const float* __restrict__ dis,
                                                 const float* __restrict__ bias, float* __restrict__ out,
                                                 float* __restrict__ out2, int N) {
    int wid = (int)((blockIdx.x * blockDim.x + threadIdx.x) >> 6);   // wave id = node
    int lane = threadIdx.x & 63;
    if (wid >= N) return;
    int n = wid;
    int f = lane;
    float d = dis[n];
    float acc = 0.0f;
    if (f < F) acc = d * d * hw[(size_t)n * 64 + f];   // self loop (weight 1)

    int beg = rowp[n];
    int c = cnt[n];
    for (int base = 0; base < c; base += 64) {
        int m = min(64, c - base);
        int es = 0; float ewv = 0.0f;
        if (lane < m) {
            es = csr_s[beg + base + lane];
            ewv = csr_w[beg + base + lane];
        }
        for (int j = 0; j < m; ++j) {
            int s = __shfl(es, j);
            float w = __shfl(ewv, j);
            if (f < F) acc = fmaf(w, hw[(size_t)s * 64 + f], acc);
        }
    }
    if (f < F) {
        float r = acc + bias[f];
        if (RELU) r = fmaxf(r, 0.0f);
        out[(size_t)n * F + f] = r;
        if (DUP) out2[(size_t)n * F + f] = r;
    }
}

// ---------------- log-softmax over 16 classes ----------------

__global__ __launch_bounds__(256) void logsoftmax16(const float* __restrict__ logits,
                                                    float* __restrict__ out, int N) {
    int g = blockIdx.x * blockDim.x + threadIdx.x;
    int node = g >> 4;
    if (node >= N) return;
    float x = logits[g];
    float m = x;
    #pragma unroll
    for (int o = 1; o < 16; o <<= 1) m = fmaxf(m, __shfl_xor(m, o));
    float e = __expf(x - m);
    float ssum = e;
    #pragma unroll
    for (int o = 1; o < 16; o <<= 1) ssum += __shfl_xor(ssum, o);
    out[g] = x - m - __logf(ssum);
}

// ---------------- launch ----------------

extern "C" void kernel_launch(void* const* d_in, const int* in_sizes, int n_in,
                              void* d_out, int out_size, void* d_ws, size_t ws_size,
                              hipStream_t stream) {
    const float* x   = (const float*)d_in[0];
    const int*   ei  = (const int*)d_in[1];
    const float* ew  = (const float*)d_in[2];
    const float* W1  = (const float*)d_in[3];
    const float* b1  = (const float*)d_in[4];
    const float* W2  = (const float*)d_in[5];
    const float* b2  = (const float*)d_in[6];
    const float* W3  = (const float*)d_in[7];
    const float* b3  = (const float*)d_in[8];
    float* out = (float*)d_out;

    const int N = in_sizes[0] / N_FEAT;      // 100000
    const int E = in_sizes[2];               // 1600000

    // workspace carve-up
    size_t off = 0;
    auto alloc = [&](size_t bytes) {
        void* p = (char*)d_ws + off;
        off += (bytes + 255) & ~(size_t)255;
        return p;
    };
    float* deg_dis = (float*)alloc((size_t)N * 4);
    int*   cnt     = (int*)alloc((size_t)N * 4);
    int*   rowp    = (int*)alloc((size_t)N * 4);
    int*   fill    = (int*)alloc((size_t)N * 4);
    int*   cursor  = (int*)alloc(256);
    int*   csr_s   = (int*)alloc((size_t)E * 4);
    float* csr_w   = (float*)alloc((size_t)E * 4);
    float* bufA    = (float*)alloc((size_t)N * 64 * 4);
    float* bufB    = (float*)alloc((size_t)N * 64 * 4);
    float* W3p     = (float*)alloc(64 * 64 * 4);

    const int TB = 256;
    int nblk = (N + TB - 1) / TB;
    int eblk = (E + TB - 1) / TB;

    // CSR build
    init_nodes<<<nblk, TB, 0, stream>>>(deg_dis, cnt, fill, cursor, N);
    edge_deg<<<eblk, TB, 0, stream>>>(ei, ew, deg_dis, cnt, E);
    node_scan<<<nblk, TB, 0, stream>>>(deg_dis, cnt, rowp, cursor, N);
    fill_csr<<<eblk, TB, 0, stream>>>(ei, ew, deg_dis, rowp, fill, csr_s, csr_w, E);
    pad_w3<<<16, TB, 0, stream>>>(W3, W3p);

    int gblk = (N + 63) / 64;                 // gemm blocks (64 rows each)
    int ablk = (N * 64 + TB - 1) / TB;        // aggregate: one wave per node

    float* logits = out + (size_t)N * 16;
    float* logits2 = out + (size_t)2 * N * 16;

    // layer 1: hw = x@W1 -> bufB ; h1 = agg(relu) -> bufA
    gemm64<<<gblk, TB, 0, stream>>>(x, W1, bufB, N);
    aggregate<64, true, false><<<ablk, TB, 0, stream>>>(bufB, rowp, cnt, csr_s, csr_w, deg_dis, b1, bufA, nullptr, N);
    // layer 2
    gemm64<<<gblk, TB, 0, stream>>>(bufA, W2, bufB, N);
    aggregate<64, true, false><<<ablk, TB, 0, stream>>>(bufB, rowp, cnt, csr_s, csr_w, deg_dis, b2, bufA, nullptr, N);
    // layer 3 (W3 padded to 64 cols; aggregate picks first 16)
    gemm64<<<gblk, TB, 0, stream>>>(bufA, W3p, bufB, N);
    aggregate<16, false, true><<<ablk, TB, 0, stream>>>(bufB, rowp, cnt, csr_s, csr_w, deg_dis, b3, logits, logits2, N);

    // log-softmax -> out region 0
    int lsblk = (N * 16 + TB - 1) / TB;
    logsoftmax16<<<lsblk, TB, 0, stream>>>(logits, out, N);
}

// Round 2
// 682.164 us; speedup vs baseline: 1.0548x; 1.0548x over previous
//
#include <hip/hip_runtime.h>
#include <hip/hip_bf16.h>

#define N_FEAT 64

// ---------------- CSR build ----------------

__global__ __launch_bounds__(256) void init_nodes(int* cnt, int* fill, int* cursor, int N) {
    int i = blockIdx.x * blockDim.x + threadIdx.x;
    if (i < N) { cnt[i] = 0; fill[i] = 0; }
    if (i == 0) cursor[0] = 0;
}

// histogram of dst (1 atomic per edge)
__global__ __launch_bounds__(256) void hist(const int* __restrict__ ei, int* cnt, int E) {
    int e = blockIdx.x * blockDim.x + threadIdx.x;
    if (e < E) atomicAdd(&cnt[ei[E + e]], 1);
}

// per-wave scan of counts + atomic cursor to get row_ptr
__global__ __launch_bounds__(256) void node_scan(const int* __restrict__ cnt,
                                                 int* __restrict__ rowp, int* cursor, int N) {
    int i = blockIdx.x * blockDim.x + threadIdx.x;
    int lane = threadIdx.x & 63;
    int c = (i < N) ? cnt[i] : 0;
    int incl = c;
    #pragma unroll
    for (int o = 1; o < 64; o <<= 1) {
        int t = __shfl_up(incl, o);
        if (lane >= o) incl += t;
    }
    int total = __shfl(incl, 63);
    int base = 0;
    if (lane == 0) base = atomicAdd(cursor, total);
    base = __shfl(base, 0);
    if (i < N) rowp[i] = base + incl - c;
}

// scatter edges into CSR, storing raw weight (one 8B store + 1 atomic per edge)
__global__ __launch_bounds__(256) void fill_csr(const int* __restrict__ ei, const float* __restrict__ ew,
                                                const int* __restrict__ rowp, int* fill,
                                                int2* __restrict__ csr, int E) {
    int e = blockIdx.x * blockDim.x + threadIdx.x;
    if (e >= E) return;
    int s = ei[e];
    int d = ei[E + e];
    int pos = rowp[d] + atomicAdd(&fill[d], 1);
    csr[pos] = make_int2(s, __float_as_int(ew[e]));
}

// deg[n] = 1 + sum of raw weights in row n (coalesced-ish, no atomics); dis = rsqrt(deg)
__global__ __launch_bounds__(256) void deg_dis_k(const int2* __restrict__ csr, const int* __restrict__ rowp,
                                                 const int* __restrict__ cnt, float* __restrict__ dis, int N) {
    int n = blockIdx.x * blockDim.x + threadIdx.x;
    if (n >= N) return;
    int beg = rowp[n], c = cnt[n];
    float s = 1.0f;                           // self loop weight
    for (int i = 0; i < c; ++i) s += __int_as_float(csr[beg + i].y);
    dis[n] = rsqrtf(s);                       // deg >= 1 always
}

__global__ __launch_bounds__(256) void pad_w3(const float* __restrict__ W3, float* __restrict__ W3p) {
    int i = blockIdx.x * blockDim.x + threadIdx.x;   // 4096 threads
    if (i >= 64 * 64) return;
    int k = i >> 6, c = i & 63;
    W3p[i] = (c < 16) ? W3[k * 16 + c] : 0.0f;
}

// ---------------- GEMM: C[N x 64] = A[N x 64] @ W[64 x 64] ----------------

__global__ __launch_bounds__(256) void gemm64(const float* __restrict__ A, const float* __restrict__ W,
                                              float* __restrict__ C, int N) {
    __shared__ float At[64 * 68];   // transposed A tile, stride 68 (bank-conflict pad, 16B aligned)
    __shared__ float Wl[64 * 64];
    int tid = threadIdx.x;
    int r0 = blockIdx.x * 64;

    // stage W (4096 floats)
    for (int i = tid * 4; i < 4096; i += 1024) {
        *(float4*)&Wl[i] = *(const float4*)&W[i];
    }
    // stage A tile transposed: At[c][r]
    #pragma unroll
    for (int jj = 0; jj < 4; ++jj) {
        int r = (tid >> 4) + jj * 16;        // 0..63
        int c0 = (tid & 15) * 4;
        float4 v = make_float4(0.f, 0.f, 0.f, 0.f);
        if (r0 + r < N) v = *(const float4*)&A[(size_t)(r0 + r) * 64 + c0];
        At[(c0 + 0) * 68 + r] = v.x;
        At[(c0 + 1) * 68 + r] = v.y;
        At[(c0 + 2) * 68 + r] = v.z;
        At[(c0 + 3) * 68 + r] = v.w;
    }
    __syncthreads();

    int tr = tid >> 4, tc = tid & 15;        // 16x16 threads, 4x4 tile each
    float acc[4][4] = {};
    #pragma unroll
    for (int k = 0; k < 64; ++k) {
        float4 a = *(const float4*)&At[k * 68 + 4 * tr];
        float4 w = *(const float4*)&Wl[k * 64 + 4 * tc];
        float av[4] = {a.x, a.y, a.z, a.w};
        float wv[4] = {w.x, w.y, w.z, w.w};
        #pragma unroll
        for (int i = 0; i < 4; ++i)
            #pragma unroll
            for (int j = 0; j < 4; ++j)
                acc[i][j] = fmaf(av[i], wv[j], acc[i][j]);
    }

    #pragma unroll
    for (int i = 0; i < 4; ++i) {
        int r = r0 + 4 * tr + i;
        if (r < N) {
            float4 v = make_float4(acc[i][0], acc[i][1], acc[i][2], acc[i][3]);
            *(float4*)&C[(size_t)r * 64 + 4 * tc] = v;
        }
    }
}

// ---------------- Aggregation: out[n] = sum_{e->n} dis[s]*ew*dis[n] * hw[s] + dis[n]^2*hw[n] + b ----------------

template<int F, bool RELU, bool DUP>
__global__ __launch_bounds__(256) void aggregate(const float* __restrict__ hw, const int* __restrict__ rowp,
                                                 const int* __restrict__ cnt, const int2* __restrict__ csr,
                                                 const float* __restrict__ dis,
                                                 const float* __restrict__ bias, float* __restrict__ out,
                                                 float* __restrict__ out2, int N) {
    int wid = (int)((blockIdx.x * blockDim.x + threadIdx.x) >> 6);   // wave id = node
    int lane = threadIdx.x & 63;
    if (wid >= N) return;
    int n = wid;
    int f = lane;
    float dd = dis[n];
    float acc = 0.0f;
    if (f < F) acc = dd * dd * hw[(size_t)n * 64 + f];   // self loop (weight 1)

    int beg = rowp[n];
    int c = cnt[n];
    for (int base = 0; base < c; base += 64) {
        int m = min(64, c - base);
        int es = 0; float wv = 0.0f;
        if (lane < m) {
            int2 ent = csr[beg + base + lane];
            es = ent.x;
            wv = __int_as_float(ent.y) * dis[ent.x] * dd;   // norm on the fly
        }
        for (int j = 0; j < m; ++j) {
            int s = __shfl(es, j);
            float w = __shfl(wv, j);
            if (f < F) acc = fmaf(w, hw[(size_t)s * 64 + f], acc);
        }
    }
    if (f < F) {
        float r = acc + bias[f];
        if (RELU) r = fmaxf(r, 0.0f);
        out[(size_t)n * F + f] = r;
        if (DUP) out2[(size_t)n * F + f] = r;
    }
}

// ---------------- log-softmax over 16 classes ----------------

__global__ __launch_bounds__(256) void logsoftmax16(const float* __restrict__ logits,
                                                    float* __restrict__ out, int N) {
    int g = blockIdx.x * blockDim.x + threadIdx.x;
    int node = g >> 4;
    if (node >= N) return;
    float x = logits[g];
    float m = x;
    #pragma unroll
    for (int o = 1; o < 16; o <<= 1) m = fmaxf(m, __shfl_xor(m, o));
    float e = __expf(x - m);
    float ssum = e;
    #pragma unroll
    for (int o = 1; o < 16; o <<= 1) ssum += __shfl_xor(ssum, o);
    out[g] = x - m - __logf(ssum);
}

// ---------------- launch ----------------

extern "C" void kernel_launch(void* const* d_in, const int* in_sizes, int n_in,
                              void* d_out, int out_size, void* d_ws, size_t ws_size,
                              hipStream_t stream) {
    const float* x   = (const float*)d_in[0];
    const int*   ei  = (const int*)d_in[1];
    const float* ew  = (const float*)d_in[2];
    const float* W1  = (const float*)d_in[3];
    const float* b1  = (const float*)d_in[4];
    const float* W2  = (const float*)d_in[5];
    const float* b2  = (const float*)d_in[6];
    const float* W3  = (const float*)d_in[7];
    const float* b3  = (const float*)d_in[8];
    float* out = (float*)d_out;

    const int N = in_sizes[0] / N_FEAT;      // 100000
    const int E = in_sizes[2];               // 1600000

    // workspace carve-up
    size_t off = 0;
    auto alloc = [&](size_t bytes) {
        void* p = (char*)d_ws + off;
        off += (bytes + 255) & ~(size_t)255;
        return p;
    };
    float* dis     = (float*)alloc((size_t)N * 4);
    int*   cnt     = (int*)alloc((size_t)N * 4);
    int*   rowp    = (int*)alloc((size_t)N * 4);
    int*   fill    = (int*)alloc((size_t)N * 4);
    int*   cursor  = (int*)alloc(256);
    int2*  csr     = (int2*)alloc((size_t)E * 8);
    float* bufA    = (float*)alloc((size_t)N * 64 * 4);
    float* bufB    = (float*)alloc((size_t)N * 64 * 4);
    float* W3p     = (float*)alloc(64 * 64 * 4);

    const int TB = 256;
    int nblk = (N + TB - 1) / TB;
    int eblk = (E + TB - 1) / TB;

    // CSR build
    init_nodes<<<nblk, TB, 0, stream>>>(cnt, fill, cursor, N);
    hist<<<eblk, TB, 0, stream>>>(ei, cnt, E);
    node_scan<<<nblk, TB, 0, stream>>>(cnt, rowp, cursor, N);
    fill_csr<<<eblk, TB, 0, stream>>>(ei, ew, rowp, fill, csr, E);
    deg_dis_k<<<nblk, TB, 0, stream>>>(csr, rowp, cnt, dis, N);
    pad_w3<<<16, TB, 0, stream>>>(W3, W3p);

    int gblk = (N + 63) / 64;                 // gemm blocks (64 rows each)
    int ablk = (N * 64 + TB - 1) / TB;        // aggregate: one wave per node

    float* logits = out + (size_t)N * 16;
    float* logits2 = out + (size_t)2 * N * 16;

    // layer 1: hw = x@W1 -> bufB ; h1 = agg(relu) -> bufA
    gemm64<<<gblk, TB, 0, stream>>>(x, W1, bufB, N);
    aggregate<64, true, false><<<ablk, TB, 0, stream>>>(bufB, rowp, cnt, csr, dis, b1, bufA, nullptr, N);
    // layer 2
    gemm64<<<gblk, TB, 0, stream>>>(bufA, W2, bufB, N);
    aggregate<64, true, false><<<ablk, TB, 0, stream>>>(bufB, rowp, cnt, csr, dis, b2, bufA, nullptr, N);
    // layer 3 (W3 padded to 64 cols; aggregate picks first 16)
    gemm64<<<gblk, TB, 0, stream>>>(bufA, W3p, bufB, N);
    aggregate<16, false, true><<<ablk, TB, 0, stream>>>(bufB, rowp, cnt, csr, dis, b3, logits, logits2, N);

    // log-softmax -> out region 0
    int lsblk = (N * 16 + TB - 1) / TB;
    logsoftmax16<<<lsblk, TB, 0, stream>>>(logits, out, N);
}

// Round 4
// 544.536 us; speedup vs baseline: 1.3214x; 1.2527x over previous
//
#include <hip/hip_runtime.h>
#include <hip/hip_bf16.h>

#define N_FEAT 64

// ---------------- CSR build ----------------

__global__ __launch_bounds__(256) void init_nodes(int* cnt, int* fill, int* cursor, int N) {
    int i = blockIdx.x * blockDim.x + threadIdx.x;
    if (i < N) { cnt[i] = 0; fill[i] = 0; }
    if (i == 0) cursor[0] = 0;
}

// histogram of dst (1 atomic per edge)
__global__ __launch_bounds__(256) void hist(const int* __restrict__ ei, int* cnt, int E) {
    int e = blockIdx.x * blockDim.x + threadIdx.x;
    if (e < E) atomicAdd(&cnt[ei[E + e]], 1);
}

// per-wave scan of counts + atomic cursor to get row_ptr
__global__ __launch_bounds__(256) void node_scan(const int* __restrict__ cnt,
                                                 int* __restrict__ rowp, int* cursor, int N) {
    int i = blockIdx.x * blockDim.x + threadIdx.x;
    int lane = threadIdx.x & 63;
    int c = (i < N) ? cnt[i] : 0;
    int incl = c;
    #pragma unroll
    for (int o = 1; o < 64; o <<= 1) {
        int t = __shfl_up(incl, o);
        if (lane >= o) incl += t;
    }
    int total = __shfl(incl, 63);
    int base = 0;
    if (lane == 0) base = atomicAdd(cursor, total);
    base = __shfl(base, 0);
    if (i < N) rowp[i] = base + incl - c;
}

// scatter edges into CSR, storing raw weight (one 8B store + 1 atomic per edge)
__global__ __launch_bounds__(256) void fill_csr(const int* __restrict__ ei, const float* __restrict__ ew,
                                                const int* __restrict__ rowp, int* fill,
                                                int2* __restrict__ csr, int E) {
    int e = blockIdx.x * blockDim.x + threadIdx.x;
    if (e >= E) return;
    int s = ei[e];
    int d = ei[E + e];
    int pos = rowp[d] + atomicAdd(&fill[d], 1);
    csr[pos] = make_int2(s, __float_as_int(ew[e]));
}

// deg[n] = 1 + sum of raw weights in row n (no atomics); dis = rsqrt(deg)
__global__ __launch_bounds__(256) void deg_dis_k(const int2* __restrict__ csr, const int* __restrict__ rowp,
                                                 const int* __restrict__ cnt, float* __restrict__ dis, int N) {
    int n = blockIdx.x * blockDim.x + threadIdx.x;
    if (n >= N) return;
    int beg = rowp[n], c = cnt[n];
    float s = 1.0f;                           // self loop weight
    for (int i = 0; i < c; ++i) s += __int_as_float(csr[beg + i].y);
    dis[n] = rsqrtf(s);                       // deg >= 1 always
}

__global__ __launch_bounds__(256) void pad_w3(const float* __restrict__ W3, float* __restrict__ W3p) {
    int i = blockIdx.x * blockDim.x + threadIdx.x;   // 4096 threads
    if (i >= 64 * 64) return;
    int k = i >> 6, c = i & 63;
    W3p[i] = (c < 16) ? W3[k * 16 + c] : 0.0f;
}

// ---------------- GEMM: C[N x 64] = A[N x 64] @ W[64 x 64] ----------------

__global__ __launch_bounds__(256) void gemm64(const float* __restrict__ A, const float* __restrict__ W,
                                              float* __restrict__ C, int N) {
    __shared__ float At[64 * 68];   // transposed A tile, stride 68 (bank-conflict pad)
    __shared__ float Wl[64 * 64];
    int tid = threadIdx.x;
    int r0 = blockIdx.x * 64;

    for (int i = tid * 4; i < 4096; i += 1024) {
        *(float4*)&Wl[i] = *(const float4*)&W[i];
    }
    #pragma unroll
    for (int jj = 0; jj < 4; ++jj) {
        int r = (tid >> 4) + jj * 16;        // 0..63
        int c0 = (tid & 15) * 4;
        float4 v = make_float4(0.f, 0.f, 0.f, 0.f);
        if (r0 + r < N) v = *(const float4*)&A[(size_t)(r0 + r) * 64 + c0];
        At[(c0 + 0) * 68 + r] = v.x;
        At[(c0 + 1) * 68 + r] = v.y;
        At[(c0 + 2) * 68 + r] = v.z;
        At[(c0 + 3) * 68 + r] = v.w;
    }
    __syncthreads();

    int tr = tid >> 4, tc = tid & 15;        // 16x16 threads, 4x4 tile each
    float acc[4][4] = {};
    #pragma unroll
    for (int k = 0; k < 64; ++k) {
        float4 a = *(const float4*)&At[k * 68 + 4 * tr];
        float4 w = *(const float4*)&Wl[k * 64 + 4 * tc];
        float av[4] = {a.x, a.y, a.z, a.w};
        float wv[4] = {w.x, w.y, w.z, w.w};
        #pragma unroll
        for (int i = 0; i < 4; ++i)
            #pragma unroll
            for (int j = 0; j < 4; ++j)
                acc[i][j] = fmaf(av[i], wv[j], acc[i][j]);
    }

    #pragma unroll
    for (int i = 0; i < 4; ++i) {
        int r = r0 + 4 * tr + i;
        if (r < N) {
            float4 v = make_float4(acc[i][0], acc[i][1], acc[i][2], acc[i][3]);
            *(float4*)&C[(size_t)r * 64 + 4 * tc] = v;
        }
    }
}

// ---------------- Aggregation ----------------
// out[n] = sum_{e->n} dis[s]*ew*dis[n] * hw[s][0:F] + dis[n]^2*hw[n][0:F] + b
// One wave per node. LPR = F/4 lanes cover a row via float4; EPB = 64/LPR
// edges in flight per step. NOTE: all __shfl are executed UNCONDITIONALLY
// (ds_bpermute needs source lanes active); masking applies to the RESULT.

template<int F, bool RELU, bool DUP>
__global__ __launch_bounds__(256) void aggregate(const float* __restrict__ hw, const int* __restrict__ rowp,
                                                 const int* __restrict__ cnt, const int2* __restrict__ csr,
                                                 const float* __restrict__ dis,
                                                 const float* __restrict__ bias, float* __restrict__ out,
                                                 float* __restrict__ out2, int N) {
    constexpr int LPR = F / 4;        // lanes per row (16 for F=64, 4 for F=16)
    constexpr int EPB = 64 / LPR;     // edges in flight (4 or 16)

    int wid = (int)((blockIdx.x * blockDim.x + threadIdx.x) >> 6);   // wave id = node
    int lane = threadIdx.x & 63;
    if (wid >= N) return;
    int n = wid;
    int g = lane / LPR;               // edge slot within step
    int t = lane % LPR;               // float4 slot within row
    float dd = dis[n];

    float4 acc = make_float4(0.f, 0.f, 0.f, 0.f);
    if (g == 0) {                     // self loop (weight 1), counted once
        float4 v = *(const float4*)&hw[(size_t)n * 64 + t * 4];
        float w = dd * dd;
        acc.x = w * v.x; acc.y = w * v.y; acc.z = w * v.z; acc.w = w * v.w;
    }

    int beg = rowp[n];
    int c = cnt[n];
    for (int base = 0; base < c; base += 64) {
        int m = min(64, c - base);
        int es = 0; float wv = 0.0f;
        if (lane < m) {
            int2 ent = csr[beg + base + lane];
            es = ent.x;
            wv = __int_as_float(ent.y) * dis[ent.x] * dd;   // norm on the fly
        }
        for (int j = 0; j < m; j += EPB) {
            int idx = j + g;
            int ic = min(idx, m - 1);
            int s = __shfl(es, ic);          // unconditional: all lanes publish
            float wr = __shfl(wv, ic);       // unconditional: all lanes publish
            float w = (idx < m) ? wr : 0.0f; // mask the RESULT, not the shuffle
            float4 v = *(const float4*)&hw[(size_t)s * 64 + t * 4];
            acc.x = fmaf(w, v.x, acc.x);
            acc.y = fmaf(w, v.y, acc.y);
            acc.z = fmaf(w, v.z, acc.z);
            acc.w = fmaf(w, v.w, acc.w);
        }
    }

    // reduce across edge slots
    #pragma unroll
    for (int off = LPR; off < 64; off <<= 1) {
        acc.x += __shfl_xor(acc.x, off);
        acc.y += __shfl_xor(acc.y, off);
        acc.z += __shfl_xor(acc.z, off);
        acc.w += __shfl_xor(acc.w, off);
    }

    if (g == 0) {
        float4 b = *(const float4*)&bias[t * 4];
        float4 r = make_float4(acc.x + b.x, acc.y + b.y, acc.z + b.z, acc.w + b.w);
        if (RELU) {
            r.x = fmaxf(r.x, 0.f); r.y = fmaxf(r.y, 0.f);
            r.z = fmaxf(r.z, 0.f); r.w = fmaxf(r.w, 0.f);
        }
        *(float4*)&out[(size_t)n * F + t * 4] = r;
        if (DUP) *(float4*)&out2[(size_t)n * F + t * 4] = r;
    }
}

// ---------------- log-softmax over 16 classes ----------------

__global__ __launch_bounds__(256) void logsoftmax16(const float* __restrict__ logits,
                                                    float* __restrict__ out, int N) {
    int g = blockIdx.x * blockDim.x + threadIdx.x;
    int node = g >> 4;
    if (node >= N) return;
    float x = logits[g];
    float m = x;
    #pragma unroll
    for (int o = 1; o < 16; o <<= 1) m = fmaxf(m, __shfl_xor(m, o));
    float e = __expf(x - m);
    float ssum = e;
    #pragma unroll
    for (int o = 1; o < 16; o <<= 1) ssum += __shfl_xor(ssum, o);
    out[g] = x - m - __logf(ssum);
}

// ---------------- launch ----------------

extern "C" void kernel_launch(void* const* d_in, const int* in_sizes, int n_in,
                              void* d_out, int out_size, void* d_ws, size_t ws_size,
                              hipStream_t stream) {
    const float* x   = (const float*)d_in[0];
    const int*   ei  = (const int*)d_in[1];
    const float* ew  = (const float*)d_in[2];
    const float* W1  = (const float*)d_in[3];
    const float* b1  = (const float*)d_in[4];
    const float* W2  = (const float*)d_in[5];
    const float* b2  = (const float*)d_in[6];
    const float* W3  = (const float*)d_in[7];
    const float* b3  = (const float*)d_in[8];
    float* out = (float*)d_out;

    const int N = in_sizes[0] / N_FEAT;      // 100000
    const int E = in_sizes[2];               // 1600000

    size_t off = 0;
    auto alloc = [&](size_t bytes) {
        void* p = (char*)d_ws + off;
        off += (bytes + 255) & ~(size_t)255;
        return p;
    };
    float* dis     = (float*)alloc((size_t)N * 4);
    int*   cnt     = (int*)alloc((size_t)N * 4);
    int*   rowp    = (int*)alloc((size_t)N * 4);
    int*   fill    = (int*)alloc((size_t)N * 4);
    int*   cursor  = (int*)alloc(256);
    int2*  csr     = (int2*)alloc((size_t)E * 8);
    float* bufA    = (float*)alloc((size_t)N * 64 * 4);
    float* bufB    = (float*)alloc((size_t)N * 64 * 4);
    float* W3p     = (float*)alloc(64 * 64 * 4);

    const int TB = 256;
    int nblk = (N + TB - 1) / TB;
    int eblk = (E + TB - 1) / TB;

    // CSR build
    init_nodes<<<nblk, TB, 0, stream>>>(cnt, fill, cursor, N);
    hist<<<eblk, TB, 0, stream>>>(ei, cnt, E);
    node_scan<<<nblk, TB, 0, stream>>>(cnt, rowp, cursor, N);
    fill_csr<<<eblk, TB, 0, stream>>>(ei, ew, rowp, fill, csr, E);
    deg_dis_k<<<nblk, TB, 0, stream>>>(csr, rowp, cnt, dis, N);
    pad_w3<<<16, TB, 0, stream>>>(W3, W3p);

    int gblk = (N + 63) / 64;                 // gemm blocks (64 rows each)
    int ablk = (N * 64 + TB - 1) / TB;        // aggregate: one wave per node

    float* logits = out + (size_t)N * 16;
    float* logits2 = out + (size_t)2 * N * 16;

    // layer 1
    gemm64<<<gblk, TB, 0, stream>>>(x, W1, bufB, N);
    aggregate<64, true, false><<<ablk, TB, 0, stream>>>(bufB, rowp, cnt, csr, dis, b1, bufA, nullptr, N);
    // layer 2
    gemm64<<<gblk, TB, 0, stream>>>(bufA, W2, bufB, N);
    aggregate<64, true, false><<<ablk, TB, 0, stream>>>(bufB, rowp, cnt, csr, dis, b2, bufA, nullptr, N);
    // layer 3 (W3 padded to 64 cols; aggregate reads first 16)
    gemm64<<<gblk, TB, 0, stream>>>(bufA, W3p, bufB, N);
    aggregate<16, false, true><<<ablk, TB, 0, stream>>>(bufB, rowp, cnt, csr, dis, b3, logits, logits2, N);

    // log-softmax -> out region 0
    int lsblk = (N * 16 + TB - 1) / TB;
    logsoftmax16<<<lsblk, TB, 0, stream>>>(logits, out, N);
}

// Round 5
// 417.159 us; speedup vs baseline: 1.7248x; 1.3053x over previous
//
#include <hip/hip_runtime.h>
#include <hip/hip_bf16.h>

#define N_FEAT 64
#define NBW 9                      // log2(nodes per bucket) = 512
#define SRC_BITS 23                // key = (dstLocal << 23) | src ; src < 2^23

// ---------------- CSR build: two-level bucket partition ----------------

// coarse histogram of dst>>NBW (LDS-staged; ~100K global atomics total)
__global__ __launch_bounds__(256) void coarse_hist(const int* __restrict__ ei, int* bcnt, int E, int NB) {
    __shared__ int h[256];
    int tid = threadIdx.x;
    h[tid] = 0;
    __syncthreads();
    for (int e = blockIdx.x * blockDim.x + tid; e < E; e += gridDim.x * blockDim.x)
        atomicAdd(&h[ei[E + e] >> NBW], 1);
    __syncthreads();
    if (tid < NB && h[tid]) atomicAdd(&bcnt[tid], h[tid]);
}

// exclusive scan of NB (<=256) bucket counts, one block
__global__ __launch_bounds__(256) void coarse_scan(const int* __restrict__ bcnt, int* boff, int* bcur, int NB) {
    __shared__ int wsum[4];
    int tid = threadIdx.x, lane = tid & 63, w = tid >> 6;
    int v = (tid < NB) ? bcnt[tid] : 0;
    int incl = v;
    #pragma unroll
    for (int o = 1; o < 64; o <<= 1) { int t = __shfl_up(incl, o); if (lane >= o) incl += t; }
    if (lane == 63) wsum[w] = incl;
    __syncthreads();
    int add = 0;
    #pragma unroll
    for (int i = 0; i < 4; ++i) if (i < w) add += wsum[i];
    int excl = add + incl - v;
    if (tid < NB) { boff[tid] = excl; bcur[tid] = excl; }
}

// partition edges into bucket-contiguous ebuf (packed key + raw weight)
__global__ __launch_bounds__(256) void partition(const int* __restrict__ ei, const float* __restrict__ ew,
                                                 int* bcur, int2* __restrict__ ebuf, int E, int NB) {
    constexpr int EPT = 8;
    __shared__ int cnt[256];
    __shared__ int base[256];
    int tid = threadIdx.x;
    cnt[tid] = 0;
    __syncthreads();
    int start = blockIdx.x * (256 * EPT);

    int d[EPT], r[EPT], s[EPT]; float w[EPT];
    #pragma unroll
    for (int i = 0; i < EPT; ++i) {
        int e = start + i * 256 + tid;
        if (e < E) {
            d[i] = ei[E + e];
            s[i] = ei[e];
            w[i] = ew[e];
            r[i] = atomicAdd(&cnt[d[i] >> NBW], 1);
        } else d[i] = -1;
    }
    __syncthreads();
    if (tid < NB && cnt[tid]) base[tid] = atomicAdd(&bcur[tid], cnt[tid]);
    __syncthreads();
    #pragma unroll
    for (int i = 0; i < EPT; ++i) {
        if (d[i] >= 0) {
            int b = d[i] >> NBW;
            int dl = d[i] & ((1 << NBW) - 1);
            int key = (dl << SRC_BITS) | s[i];
            ebuf[base[b] + r[i]] = make_int2(key, __float_as_int(w[i]));
        }
    }
}

// one block per bucket: per-node hist + weight-sum (LDS), scan, emit rowp/cnt/dis,
// then scatter edges into the bucket's contiguous CSR slice (L2-local)
__global__ __launch_bounds__(256) void bucket_csr(const int2* __restrict__ ebuf, const int* __restrict__ boff,
                                                  const int* __restrict__ bcnt,
                                                  int2* __restrict__ csr, int* __restrict__ rowp,
                                                  int* __restrict__ cnt, float* __restrict__ dis, int N) {
    __shared__ int   h[512];
    __shared__ float ws[512];
    __shared__ int   off[512];
    __shared__ int   wsum[4];
    int b = blockIdx.x, tid = threadIdx.x;
    int nbase = b << NBW;
    int nn = min(512, N - nbase);
    int beg = boff[b], m = bcnt[b];

    h[tid] = 0; h[tid + 256] = 0;
    ws[tid] = 0.f; ws[tid + 256] = 0.f;
    __syncthreads();

    for (int i = tid; i < m; i += 256) {
        int2 en = ebuf[beg + i];
        int dl = ((unsigned)en.x) >> SRC_BITS;
        atomicAdd(&h[dl], 1);
        atomicAdd(&ws[dl], __int_as_float(en.y));
    }
    __syncthreads();

    // exclusive scan of 512 counters (2 per thread)
    int v0 = h[2 * tid], v1 = h[2 * tid + 1];
    int v = v0 + v1;
    int lane = tid & 63, wv = tid >> 6;
    int incl = v;
    #pragma unroll
    for (int o = 1; o < 64; o <<= 1) { int t = __shfl_up(incl, o); if (lane >= o) incl += t; }
    if (lane == 63) wsum[wv] = incl;
    __syncthreads();
    int add = 0;
    #pragma unroll
    for (int i = 0; i < 4; ++i) if (i < wv) add += wsum[i];
    int excl = add + incl - v;
    off[2 * tid] = excl;
    off[2 * tid + 1] = excl + v0;
    __syncthreads();

    for (int l = tid; l < nn; l += 256) {
        rowp[nbase + l] = beg + off[l];
        cnt[nbase + l]  = h[l];
        dis[nbase + l]  = rsqrtf(1.0f + ws[l]);   // self-loop weight 1
    }
    __syncthreads();
    h[tid] = 0; h[tid + 256] = 0;                 // reuse as fill cursors
    __syncthreads();

    for (int i = tid; i < m; i += 256) {
        int2 en = ebuf[beg + i];
        unsigned k = (unsigned)en.x;
        int dl  = k >> SRC_BITS;
        int src = k & ((1 << SRC_BITS) - 1);
        int pos = atomicAdd(&h[dl], 1);
        csr[beg + off[dl] + pos] = make_int2(src, en.y);
    }
}

__global__ __launch_bounds__(256) void pad_w3(const float* __restrict__ W3, float* __restrict__ W3p) {
    int i = blockIdx.x * blockDim.x + threadIdx.x;
    if (i >= 64 * 64) return;
    int k = i >> 6, c = i & 63;
    W3p[i] = (c < 16) ? W3[k * 16 + c] : 0.0f;
}

// ---------------- GEMM: C[N x 64] = A[N x 64] @ W[64 x 64] ----------------

__global__ __launch_bounds__(256) void gemm64(const float* __restrict__ A, const float* __restrict__ W,
                                              float* __restrict__ C, int N) {
    __shared__ float At[64 * 68];
    __shared__ float Wl[64 * 64];
    int tid = threadIdx.x;
    int r0 = blockIdx.x * 64;

    for (int i = tid * 4; i < 4096; i += 1024) {
        *(float4*)&Wl[i] = *(const float4*)&W[i];
    }
    #pragma unroll
    for (int jj = 0; jj < 4; ++jj) {
        int r = (tid >> 4) + jj * 16;
        int c0 = (tid & 15) * 4;
        float4 v = make_float4(0.f, 0.f, 0.f, 0.f);
        if (r0 + r < N) v = *(const float4*)&A[(size_t)(r0 + r) * 64 + c0];
        At[(c0 + 0) * 68 + r] = v.x;
        At[(c0 + 1) * 68 + r] = v.y;
        At[(c0 + 2) * 68 + r] = v.z;
        At[(c0 + 3) * 68 + r] = v.w;
    }
    __syncthreads();

    int tr = tid >> 4, tc = tid & 15;
    float acc[4][4] = {};
    #pragma unroll
    for (int k = 0; k < 64; ++k) {
        float4 a = *(const float4*)&At[k * 68 + 4 * tr];
        float4 w = *(const float4*)&Wl[k * 64 + 4 * tc];
        float av[4] = {a.x, a.y, a.z, a.w};
        float wv[4] = {w.x, w.y, w.z, w.w};
        #pragma unroll
        for (int i = 0; i < 4; ++i)
            #pragma unroll
            for (int j = 0; j < 4; ++j)
                acc[i][j] = fmaf(av[i], wv[j], acc[i][j]);
    }

    #pragma unroll
    for (int i = 0; i < 4; ++i) {
        int r = r0 + 4 * tr + i;
        if (r < N) {
            float4 v = make_float4(acc[i][0], acc[i][1], acc[i][2], acc[i][3]);
            *(float4*)&C[(size_t)r * 64 + 4 * tc] = v;
        }
    }
}

// ---------------- Aggregation (unchanged from R3) ----------------

template<int F, bool RELU, bool DUP>
__global__ __launch_bounds__(256) void aggregate(const float* __restrict__ hw, const int* __restrict__ rowp,
                                                 const int* __restrict__ cnt, const int2* __restrict__ csr,
                                                 const float* __restrict__ dis,
                                                 const float* __restrict__ bias, float* __restrict__ out,
                                                 float* __restrict__ out2, int N) {
    constexpr int LPR = F / 4;
    constexpr int EPB = 64 / LPR;

    int wid = (int)((blockIdx.x * blockDim.x + threadIdx.x) >> 6);
    int lane = threadIdx.x & 63;
    if (wid >= N) return;
    int n = wid;
    int g = lane / LPR;
    int t = lane % LPR;
    float dd = dis[n];

    float4 acc = make_float4(0.f, 0.f, 0.f, 0.f);
    if (g == 0) {
        float4 v = *(const float4*)&hw[(size_t)n * 64 + t * 4];
        float w = dd * dd;
        acc.x = w * v.x; acc.y = w * v.y; acc.z = w * v.z; acc.w = w * v.w;
    }

    int beg = rowp[n];
    int c = cnt[n];
    for (int base = 0; base < c; base += 64) {
        int m = min(64, c - base);
        int es = 0; float wv = 0.0f;
        if (lane < m) {
            int2 ent = csr[beg + base + lane];
            es = ent.x;
            wv = __int_as_float(ent.y) * dis[ent.x] * dd;
        }
        for (int j = 0; j < m; j += EPB) {
            int idx = j + g;
            int ic = min(idx, m - 1);
            int s = __shfl(es, ic);           // unconditional shuffles
            float wr = __shfl(wv, ic);
            float w = (idx < m) ? wr : 0.0f;  // mask result only
            float4 v = *(const float4*)&hw[(size_t)s * 64 + t * 4];
            acc.x = fmaf(w, v.x, acc.x);
            acc.y = fmaf(w, v.y, acc.y);
            acc.z = fmaf(w, v.z, acc.z);
            acc.w = fmaf(w, v.w, acc.w);
        }
    }

    #pragma unroll
    for (int off = LPR; off < 64; off <<= 1) {
        acc.x += __shfl_xor(acc.x, off);
        acc.y += __shfl_xor(acc.y, off);
        acc.z += __shfl_xor(acc.z, off);
        acc.w += __shfl_xor(acc.w, off);
    }

    if (g == 0) {
        float4 b = *(const float4*)&bias[t * 4];
        float4 r = make_float4(acc.x + b.x, acc.y + b.y, acc.z + b.z, acc.w + b.w);
        if (RELU) {
            r.x = fmaxf(r.x, 0.f); r.y = fmaxf(r.y, 0.f);
            r.z = fmaxf(r.z, 0.f); r.w = fmaxf(r.w, 0.f);
        }
        *(float4*)&out[(size_t)n * F + t * 4] = r;
        if (DUP) *(float4*)&out2[(size_t)n * F + t * 4] = r;
    }
}

// ---------------- log-softmax over 16 classes ----------------

__global__ __launch_bounds__(256) void logsoftmax16(const float* __restrict__ logits,
                                                    float* __restrict__ out, int N) {
    int g = blockIdx.x * blockDim.x + threadIdx.x;
    int node = g >> 4;
    if (node >= N) return;
    float x = logits[g];
    float m = x;
    #pragma unroll
    for (int o = 1; o < 16; o <<= 1) m = fmaxf(m, __shfl_xor(m, o));
    float e = __expf(x - m);
    float ssum = e;
    #pragma unroll
    for (int o = 1; o < 16; o <<= 1) ssum += __shfl_xor(ssum, o);
    out[g] = x - m - __logf(ssum);
}

// ---------------- launch ----------------

extern "C" void kernel_launch(void* const* d_in, const int* in_sizes, int n_in,
                              void* d_out, int out_size, void* d_ws, size_t ws_size,
                              hipStream_t stream) {
    const float* x   = (const float*)d_in[0];
    const int*   ei  = (const int*)d_in[1];
    const float* ew  = (const float*)d_in[2];
    const float* W1  = (const float*)d_in[3];
    const float* b1  = (const float*)d_in[4];
    const float* W2  = (const float*)d_in[5];
    const float* b2  = (const float*)d_in[6];
    const float* W3  = (const float*)d_in[7];
    const float* b3  = (const float*)d_in[8];
    float* out = (float*)d_out;

    const int N = in_sizes[0] / N_FEAT;      // 100000
    const int E = in_sizes[2];               // 1600000
    const int NB = (N + (1 << NBW) - 1) >> NBW;   // 196 buckets (<=256)

    size_t off = 0;
    auto alloc = [&](size_t bytes) {
        void* p = (char*)d_ws + off;
        off += (bytes + 255) & ~(size_t)255;
        return p;
    };
    float* dis     = (float*)alloc((size_t)N * 4);
    int*   cnt     = (int*)alloc((size_t)N * 4);
    int*   rowp    = (int*)alloc((size_t)N * 4);
    int*   bcnt    = (int*)alloc(256 * 4);
    int*   boff    = (int*)alloc(256 * 4);
    int*   bcur    = (int*)alloc(256 * 4);
    int2*  csr     = (int2*)alloc((size_t)E * 8);
    float* bufA    = (float*)alloc((size_t)N * 64 * 4);
    float* bufB    = (float*)alloc((size_t)N * 64 * 4);
    float* W3p     = (float*)alloc(64 * 64 * 4);
    int2*  ebuf    = (int2*)bufB;            // staging reuses bufB (consumed before gemm writes it)

    const int TB = 256;

    // CSR build
    hipMemsetAsync(bcnt, 0, 256 * 4, stream);
    coarse_hist<<<512, TB, 0, stream>>>(ei, bcnt, E, NB);
    coarse_scan<<<1, TB, 0, stream>>>(bcnt, boff, bcur, NB);
    partition<<<(E + 2047) / 2048, TB, 0, stream>>>(ei, ew, bcur, ebuf, E, NB);
    bucket_csr<<<NB, TB, 0, stream>>>(ebuf, boff, bcnt, csr, rowp, cnt, dis, N);
    pad_w3<<<16, TB, 0, stream>>>(W3, W3p);

    int gblk = (N + 63) / 64;
    int ablk = (N * 64 + TB - 1) / TB;

    float* logits = out + (size_t)N * 16;
    float* logits2 = out + (size_t)2 * N * 16;

    // layer 1
    gemm64<<<gblk, TB, 0, stream>>>(x, W1, bufB, N);
    aggregate<64, true, false><<<ablk, TB, 0, stream>>>(bufB, rowp, cnt, csr, dis, b1, bufA, nullptr, N);
    // layer 2
    gemm64<<<gblk, TB, 0, stream>>>(bufA, W2, bufB, N);
    aggregate<64, true, false><<<ablk, TB, 0, stream>>>(bufB, rowp, cnt, csr, dis, b2, bufA, nullptr, N);
    // layer 3
    gemm64<<<gblk, TB, 0, stream>>>(bufA, W3p, bufB, N);
    aggregate<16, false, true><<<ablk, TB, 0, stream>>>(bufB, rowp, cnt, csr, dis, b3, logits, logits2, N);

    // log-softmax
    int lsblk = (N * 16 + TB - 1) / TB;
    logsoftmax16<<<lsblk, TB, 0, stream>>>(logits, out, N);
}